// Round 2
// baseline (211.513 us; speedup 1.0000x reference)
//
#include <hip/hip_runtime.h>
#include <stdint.h>

// Problem constants (fixed by the reference): n=8, c=16, H=W=512.
#define NIMG 8
#define NCLS 16
#define HW   262144            // 512*512 = 2^18 pixels per image
#define PXB  1024              // pixels per block tile
#define NBLK 2048              // (NIMG*HW)/PXB ; 256 blocks per image

// ---------------------------------------------------------------------------
// Main pass, streaming version. Block b owns 1024 consecutive pixels of one
// image; each thread owns 4 contiguous pixels.
//
// No LDS tile: pred has ZERO cross-thread reuse here (each thread consumes
// exactly the 16 channel values of its own 4 pixels), so the previous
// global->LDS->reg round-trip was pure overhead and its 64KB tile capped
// residency at 2 blocks/CU. Instead, register-stage all 16 channels
// (float4 v[16] = 64 VGPRs, fully unrolled -> static indexing, stays in
// registers), then run the two softmax passes in-register. 16 independent
// global_load_dwordx4 per thread are in flight; the compiler inserts
// per-use vmcnt waits (no block-wide vmcnt(0) drain before compute).
// LDS use drops to 128B -> occupancy VGPR-limited (~2x previous).
// ---------------------------------------------------------------------------
__global__ __launch_bounds__(256) void dwce_main(const float* __restrict__ pred,
                                                 const int* __restrict__ tgt,
                                                 float* __restrict__ partials) {
    __shared__ float s_bin[32];          // [0..15] sum(lp_t), [16..31] count
    const int tid = threadIdx.x;
    if (tid < 32) s_bin[tid] = 0.0f;
    __syncthreads();                     // only LDS init outstanding here

    const int b = blockIdx.x;
    const long long px0 = (long long)b * PXB;      // tile start (one image)
    const int n_img = (int)(px0 >> 18);
    const int hw0   = (int)(px0 & (HW - 1));
    const float* base = pred + (size_t)n_img * NCLS * HW + hw0 + tid * 4;

    // Targets for this thread's 4 pixels.
    const int4 t4 = *(const int4*)(tgt + px0 + tid * 4);

    // Register-stage all 16 channel float4s (coalesced: 64 lanes x 16B = 1KB
    // contiguous per instruction; channel stride is 1 MiB).
    float4 v[NCLS];
#pragma unroll
    for (int c = 0; c < NCLS; ++c)
        v[c] = *(const float4*)(base + (size_t)c * HW);

    // Pass 1: componentwise max over channels + gather logit at target class.
    float4 m  = make_float4(-3.0e38f, -3.0e38f, -3.0e38f, -3.0e38f);
    float4 xt = make_float4(0.f, 0.f, 0.f, 0.f);
#pragma unroll
    for (int c = 0; c < NCLS; ++c) {
        m.x = fmaxf(m.x, v[c].x);
        m.y = fmaxf(m.y, v[c].y);
        m.z = fmaxf(m.z, v[c].z);
        m.w = fmaxf(m.w, v[c].w);
        if (t4.x == c) xt.x = v[c].x;   // -> v_cndmask, no divergence
        if (t4.y == c) xt.y = v[c].y;
        if (t4.z == c) xt.z = v[c].z;
        if (t4.w == c) xt.w = v[c].w;
    }

    // Pass 2: sum of exp(v - m). Same summation order as the LDS version ->
    // bit-identical result.
    float4 s = make_float4(0.f, 0.f, 0.f, 0.f);
#pragma unroll
    for (int c = 0; c < NCLS; ++c) {
        s.x += __expf(v[c].x - m.x);
        s.y += __expf(v[c].y - m.y);
        s.z += __expf(v[c].z - m.z);
        s.w += __expf(v[c].w - m.w);
    }

    const float lp0 = xt.x - (m.x + __logf(s.x));
    const float lp1 = xt.y - (m.y + __logf(s.y));
    const float lp2 = xt.z - (m.z + __logf(s.z));
    const float lp3 = xt.w - (m.w + __logf(s.w));

    atomicAdd(&s_bin[t4.x], lp0);
    atomicAdd(&s_bin[t4.y], lp1);
    atomicAdd(&s_bin[t4.z], lp2);
    atomicAdd(&s_bin[t4.w], lp3);
    atomicAdd(&s_bin[16 + t4.x], 1.0f);
    atomicAdd(&s_bin[16 + t4.y], 1.0f);
    atomicAdd(&s_bin[16 + t4.z], 1.0f);
    atomicAdd(&s_bin[16 + t4.w], 1.0f);

    __syncthreads();
    if (tid < 32)   // non-atomic per-block partials, c-major: partials[c][block]
        partials[(size_t)tid * NBLK + b] = s_bin[tid];
}

// ---------------------------------------------------------------------------
// Finalize: reduce 2048 block-partials per bin, build w_class from global
// counts, compute -mean_n(num/den). Single block, 256 threads.
// Image n owns blocks [n*256, (n+1)*256) -> contiguous 256 floats per (c,n).
// ---------------------------------------------------------------------------
__global__ __launch_bounds__(256) void dwce_final(const float* __restrict__ ws,
                                                  float* __restrict__ out) {
    __shared__ float tot[32][NIMG];   // [c(0..31)][n]
    __shared__ float wcl[NCLS];
    __shared__ float ratio[NIMG];
    const int tid = threadIdx.x;
    const int c = tid >> 3;           // 0..31
    const int n = tid & 7;            // 0..7

    const float4* p = (const float4*)(ws + (size_t)c * NBLK + n * 256);
    float4 a = make_float4(0.f, 0.f, 0.f, 0.f);
#pragma unroll 8
    for (int k = 0; k < 64; ++k) {
        float4 q = p[k];
        a.x += q.x; a.y += q.y; a.z += q.z; a.w += q.w;
    }
    tot[c][n] = (a.x + a.y) + (a.z + a.w);
    __syncthreads();

    if (tid < NCLS) {
        float g = 0.f;
#pragma unroll
        for (int i = 0; i < NIMG; ++i) g += tot[NCLS + tid][i];   // global count
        wcl[tid] = (g > 0.f) ? 1.0f / (g * (float)NCLS) : 0.0f;
    }
    __syncthreads();
    if (tid < NIMG) {
        float num = 0.f, den = 0.f;
#pragma unroll
        for (int c2 = 0; c2 < NCLS; ++c2) {
            num += tot[c2][tid] * wcl[c2];
            den += tot[NCLS + c2][tid] * wcl[c2];
        }
        ratio[tid] = num / den;
    }
    __syncthreads();
    if (tid == 0) {
        float r = 0.f;
#pragma unroll
        for (int i = 0; i < NIMG; ++i) r += ratio[i];
        out[0] = -r * (1.0f / (float)NIMG);
    }
}

extern "C" void kernel_launch(void* const* d_in, const int* in_sizes, int n_in,
                              void* d_out, int out_size, void* d_ws, size_t ws_size,
                              hipStream_t stream) {
    const float* pred = (const float*)d_in[0];
    const int*   tgt  = (const int*)d_in[1];
    // d_in[2] (weights) is ignored by the reference.
    float* out = (float*)d_out;
    float* ws  = (float*)d_ws;   // 32*NBLK floats = 256 KB, fully overwritten

    dwce_main<<<NBLK, 256, 0, stream>>>(pred, tgt, ws);
    dwce_final<<<1, 256, 0, stream>>>(ws, out);
}